// Round 4
// baseline (109.785 us; speedup 1.0000x reference)
//
#include <hip/hip_runtime.h>
#include <hip/hip_cooperative_groups.h>

namespace cg = cooperative_groups;

// MotionResidualBranch — collapsed-linear formulation, ONE cooperative launch.
//
// Everything from barX to U_pw is linear in 15 per-(b,t) scalars. Folded
// tables: Gt[45][256], Ht[3][256], base[256] (depthwise-conv3 + pointwise
// folded over Mfold = phi/gamma folded through WM). Then
//   U_pw[b,t,e] = base[e] + sum_j valid(t-1+j)*(H[j][e] + sum_i coef[b,t-1+j,i]*G[j][i][e])
// + LayerNorm over e.
//
// Key perf decision (r3 post-mortem): coef is read in phase B via
// WAVE-UNIFORM global addresses -> scalar loads through the constant cache,
// NOT via LDS broadcast reads (45 ds_read/t was LDS-pipe-bound, ~17us/CU).
// Coef rows padded to 16 floats so they merge into s_load_dwordx4/x8.

#define DD 256
#define KK 54
#define BB 8
#define TT 1024
#define NCOEF 15
#define CSTRIDE 16      // padded coef row (64B-aligned)
#define TS 16
#define NBT (BB * TT)
#define NTBLK 49
#define GRID 512

struct Params {
  const float *barX, *W, *phi_v_w, *phi_v_b, *phi_a_w, *phi_a_b, *gamma_v, *gamma_a;
  const float *WM_w, *WM_b, *dw_w, *dw_b, *pw_w, *pw_b, *ln_w, *ln_b;
  float *Gt, *Ht, *baset, *coef, *out;
};

__global__ __launch_bounds__(256, 2) void fused(Params P)
{
  cg::grid_group grid = cg::this_grid();
  const int gid  = blockIdx.x;
  const int tid  = threadIdx.x;
  const int wave = tid >> 6, lane = tid & 63;

  __shared__ __align__(16) float phis[DD];
  __shared__ __align__(16) float cvec[DD];
  __shared__ float wsl[4][64 * 5];
  __shared__ float red[2][4][2];

  // ---------------- Phase A ----------------
  if (gid < NTBLK) {
    // Tables: Gt[o] (o<45), Ht (45..47), base (48). Mfold inlined.
    const int o = gid;
    float cv;
    if (o < 45) {
      const int j = o / 15, i = o - j * 15, p = i / 5, q = i - p * 5;
      float v;
      if (q == 4) v = P.gamma_v[0] * P.phi_v_b[tid] + P.gamma_a[0] * P.phi_a_b[tid];
      else { const float* phi = (q < 2) ? P.phi_v_w : P.phi_a_w; v = phi[tid * 2 + (q & 1)]; }
      phis[tid] = v;
      __syncthreads();
      // mfold[i][tid] = dot(WM_w row tid, slice p ; phis)
      const float4* wrow = (const float4*)(P.WM_w + (size_t)tid * (3 * DD) + p * DD);
      const float4* ph   = (const float4*)phis;
      float acc = 0.f;
#pragma unroll 8
      for (int c = 0; c < DD / 4; ++c) {
        const float4 a = wrow[c], bq = ph[c];
        acc += a.x * bq.x + a.y * bq.y + a.z * bq.z + a.w * bq.w;
      }
      cv = P.dw_w[tid * 3 + j] * acc;
    } else if (o < 48) {
      cv = P.dw_w[tid * 3 + (o - 45)] * P.WM_b[tid];
    } else {
      cv = P.dw_b[tid];
    }
    cvec[tid] = cv;
    __syncthreads();
    const float4* prow = (const float4*)(P.pw_w + (size_t)tid * DD);
    const float4* cp   = (const float4*)cvec;
    float acc = 0.f;
#pragma unroll 8
    for (int c = 0; c < DD / 4; ++c) {
      const float4 a = prow[c], bq = cp[c];
      acc += a.x * bq.x + a.y * bq.y + a.z * bq.z + a.w * bq.w;
    }
    if (o < 45)      P.Gt[o * DD + tid] = acc;
    else if (o < 48) P.Ht[(o - 45) * DD + tid] = acc;
    else             P.baset[tid] = acc + P.pw_b[tid];
  } else {
    // coef rows -> global (padded stride 16). 18 rows/block, 5 rounds of 4.
    const int base = (gid - NTBLK) * 18;
    const float gv = P.gamma_v[0], ga = P.gamma_a[0];
    float* lds = wsl[wave];
    for (int r0 = 0; r0 < 20; r0 += 4) {
      const int r  = r0 + wave;
      const int bt = base + r;
      const bool act = (r < 18) && (bt < NBT);
      const int t = bt & (TT - 1);
      float w = 0.f, v0 = 0.f, v1 = 0.f, a0 = 0.f, a1 = 0.f;
      if (act && lane < KK) {
        w = P.W[(size_t)bt * KK + lane];
        const float2* xp = (const float2*)P.barX + ((size_t)bt * KK + lane);
        const float2 x = xp[0];
        float2 xm = make_float2(0.f, 0.f), xmm = make_float2(0.f, 0.f);
        if (t >= 1) xm  = xp[-KK];
        if (t >= 2) xmm = xp[-2 * KK];
        v0 = x.x - xm.x; v1 = x.y - xm.y;
        const float vm0 = (t >= 1) ? (xm.x - xmm.x) : 0.f;
        const float vm1 = (t >= 1) ? (xm.y - xmm.y) : 0.f;
        a0 = v0 - vm0; a1 = v1 - vm1;
      }
      float wsum = w;
#pragma unroll
      for (int m = 32; m; m >>= 1) wsum += __shfl_xor(wsum, m);
      const float wn = w * (1.f / (wsum + 1e-6f));
      lds[lane * 5 + 0] = wn * v0; lds[lane * 5 + 1] = wn * v1;
      lds[lane * 5 + 2] = wn * a0; lds[lane * 5 + 3] = wn * a1;
      lds[lane * 5 + 4] = wn;
      __syncthreads();
      if (act && lane < NCOEF) {
        const int p = lane / 5, q = lane - p * 5;
        const int k0 = (p == 0) ? 0  : ((p == 1) ? 12 : 33);
        const int k1 = (p == 0) ? 12 : ((p == 1) ? 33 : 54);
        float accv = 0.f;
        for (int k = k0; k < k1; ++k) accv += lds[k * 5 + q];
        if (q < 2) accv *= gv; else if (q < 4) accv *= ga;
        P.coef[(size_t)bt * CSTRIDE + lane] = accv;
      }
      __syncthreads();
    }
  }
  grid.sync();

  // ---------------- Phase B ----------------
  {
    const int b  = gid >> 6;
    const int t0 = (gid & 63) * TS;
    const int e  = tid;

    float Gr[45];
#pragma unroll
    for (int ji = 0; ji < 45; ++ji) Gr[ji] = P.Gt[ji * DD + e];
    const float H0 = P.Ht[0 * DD + e], H1 = P.Ht[1 * DD + e], H2 = P.Ht[2 * DD + e];
    const float bs = P.baset[e];
    const float lw = P.ln_w[e], lb = P.ln_b[e];
    const float* crow0 = P.coef + (size_t)b * TT * CSTRIDE;

    for (int tl = 0; tl < TS; ++tl) {
      const int t = t0 + tl;
      float acc = bs;
#pragma unroll
      for (int j = 0; j < 3; ++j) {
        const int gt = t + j - 1;
        if (gt >= 0 && gt < TT) {          // wave-uniform branch
          const float* cr = crow0 + (size_t)gt * CSTRIDE;  // uniform addr -> s_load
          acc += (j == 0) ? H0 : ((j == 1) ? H1 : H2);
#pragma unroll
          for (int i = 0; i < NCOEF; ++i)
            acc += cr[i] * Gr[j * NCOEF + i];
        }
      }
      // LayerNorm block reduction
      float s = acc, ss = acc * acc;
#pragma unroll
      for (int m = 32; m; m >>= 1) { s += __shfl_xor(s, m); ss += __shfl_xor(ss, m); }
      const int par = tl & 1;
      if (lane == 0) { red[par][wave][0] = s; red[par][wave][1] = ss; }
      __syncthreads();
      const float fs  = red[par][0][0] + red[par][1][0] + red[par][2][0] + red[par][3][0];
      const float fss = red[par][0][1] + red[par][1][1] + red[par][2][1] + red[par][3][1];
      const float mu  = fs * (1.f / DD);
      const float var = fss * (1.f / DD) - mu * mu;
      const float rs  = rsqrtf(var + 1e-5f);
      P.out[((size_t)b * TT + t) * DD + e] = (acc - mu) * rs * lw + lb;
    }
  }
}

extern "C" void kernel_launch(void* const* d_in, const int* in_sizes, int n_in,
                              void* d_out, int out_size, void* d_ws, size_t ws_size,
                              hipStream_t stream) {
  Params p;
  p.barX    = (const float*)d_in[0];
  p.W       = (const float*)d_in[1];
  p.phi_v_w = (const float*)d_in[2];
  p.phi_v_b = (const float*)d_in[3];
  p.phi_a_w = (const float*)d_in[4];
  p.phi_a_b = (const float*)d_in[5];
  p.gamma_v = (const float*)d_in[6];
  p.gamma_a = (const float*)d_in[7];
  p.WM_w    = (const float*)d_in[8];
  p.WM_b    = (const float*)d_in[9];
  p.dw_w    = (const float*)d_in[10];
  p.dw_b    = (const float*)d_in[11];
  p.pw_w    = (const float*)d_in[12];
  p.pw_b    = (const float*)d_in[13];
  p.ln_w    = (const float*)d_in[14];
  p.ln_b    = (const float*)d_in[15];

  float* ws = (float*)d_ws;
  p.Gt    = ws;                 // 45*256 = 11520
  p.Ht    = ws + 11520;         // 3*256  = 768
  p.baset = ws + 12288;         // 256
  p.coef  = ws + 16384;         // 8192*16 = 131072 floats (64B-aligned rows)
  p.out   = (float*)d_out;

  void* args[] = { &p };
  hipLaunchCooperativeKernel((void*)fused, dim3(GRID), dim3(256), args, 0, stream);
}

// Round 5
// 38.129 us; speedup vs baseline: 2.8793x; 2.8793x over previous
//
#include <hip/hip_runtime.h>

// MotionResidualBranch — collapsed-linear formulation, 2 kernels.
//
// Everything from barX to U_pw is linear in 15 per-(b,t) scalars
// (per part p: sum_k wn*V0, wn*V1, wn*A0, wn*A1, wn). Folding phi/gamma
// through WM, then depthwise-conv3 + pointwise, gives tables
//   G[j][i][e] (i<15), G[j][15][e] = H[j][e] (the WM_b path), base[e].
// With coef[b,t,0..14] = the 15 scalars and coef[b,t,15] = 1 (0 on the
// zero-pad rows t=-1, t=T), the main phase is branch-free:
//   U_pw[b,t,e] = base[e] + sum_{j=0..2} sum_{i=0..15} coef[b,t-1+j,i]*G[j][i][e]
// followed by LayerNorm over e.
//
// r4 post-mortem: cooperative launch was the regression (grid.sync ~90us
// + G-table scratch spill at VGPR 36/40). Separate kernels, __restrict__
// everywhere. r3 post-mortem: coef via LDS broadcast was LDS-pipe-bound;
// here coef is read via readfirstlane-forced SCALAR loads (SMEM pipe).

#define DD 256
#define KK 54
#define BB 8
#define TT 1024
#define NCOEF 15
#define CROW 16          // padded coef row (64B)
#define TROWS (TT + 2)   // one zero row before t=0 and after t=TT-1
#define TS 16
#define NBT (BB * TT)

// ---------- K_A: blocks 0..48 -> tables ; blocks 49..560 -> coef ----------
__global__ __launch_bounds__(256) void ka_tables_coef(
    const float* __restrict__ barX, const float* __restrict__ W,
    const float* __restrict__ phi_v_w, const float* __restrict__ phi_v_b,
    const float* __restrict__ phi_a_w, const float* __restrict__ phi_a_b,
    const float* __restrict__ gamma_v, const float* __restrict__ gamma_a,
    const float* __restrict__ WM_w, const float* __restrict__ WM_b,
    const float* __restrict__ dw_w, const float* __restrict__ dw_b,
    const float* __restrict__ pw_w, const float* __restrict__ pw_b,
    float* __restrict__ Gt, float* __restrict__ baset, float* __restrict__ coef)
{
  const int tid  = threadIdx.x;
  const int wave = tid >> 6, lane = tid & 63;
  __shared__ __align__(16) float sA[DD];
  __shared__ __align__(16) float sB[DD];
  __shared__ float wsl[4][64 * 5];

  if (blockIdx.x < 49) {
    // ---- tables: o = j*16+i (i<15: G via inline mfold; i==15: H), o==48: base
    const int o = blockIdx.x;
    float cv;
    if (o < 48) {
      const int j = o >> 4, i = o & 15;
      if (i < 15) {
        const int p = i / 5, q = i - p * 5;
        float v;
        if (q == 4) v = gamma_v[0] * phi_v_b[tid] + gamma_a[0] * phi_a_b[tid];
        else { const float* phi = (q < 2) ? phi_v_w : phi_a_w; v = phi[tid * 2 + (q & 1)]; }
        sA[tid] = v;
        __syncthreads();
        // mfold[i][tid] = dot(WM_w row tid slice p, sA)
        const float4* wrow = (const float4*)(WM_w + (size_t)tid * (3 * DD) + p * DD);
        const float4* ph   = (const float4*)sA;
        float m = 0.f;
#pragma unroll 8
        for (int c = 0; c < DD / 4; ++c) {
          const float4 a = wrow[c], bq = ph[c];
          m += a.x * bq.x + a.y * bq.y + a.z * bq.z + a.w * bq.w;
        }
        cv = dw_w[tid * 3 + j] * m;
      } else {
        cv = dw_w[tid * 3 + j] * WM_b[tid];
      }
    } else {
      cv = dw_b[tid];
    }
    sB[tid] = cv;
    __syncthreads();
    const float4* prow = (const float4*)(pw_w + (size_t)tid * DD);
    const float4* cp   = (const float4*)sB;
    float acc = 0.f;
#pragma unroll 8
    for (int c = 0; c < DD / 4; ++c) {
      const float4 a = prow[c], bq = cp[c];
      acc += a.x * bq.x + a.y * bq.y + a.z * bq.z + a.w * bq.w;
    }
    if (o < 48) Gt[o * DD + tid] = acc;
    else        baset[tid] = acc + pw_b[tid];
  } else {
    // ---- coef: 16 rows per block, 4 rounds of 4 waves (wave-local LDS)
    const int blk  = blockIdx.x - 49;      // 0..511
    const int base = blk * 16;
    const float gv = gamma_v[0], ga = gamma_a[0];
    float* lds = wsl[wave];
    for (int r = 0; r < 4; ++r) {
      const int bt = base + r * 4 + wave;
      const int t  = bt & (TT - 1);
      const int b  = bt >> 10;
      float w = 0.f, v0 = 0.f, v1 = 0.f, a0 = 0.f, a1 = 0.f;
      if (lane < KK) {
        w = W[(size_t)bt * KK + lane];
        const float2* xp = (const float2*)barX + ((size_t)bt * KK + lane);
        const float2 x = xp[0];
        float2 xm = make_float2(0.f, 0.f), xmm = make_float2(0.f, 0.f);
        if (t >= 1) xm  = xp[-KK];
        if (t >= 2) xmm = xp[-2 * KK];
        v0 = x.x - xm.x; v1 = x.y - xm.y;
        const float vm0 = (t >= 1) ? (xm.x - xmm.x) : 0.f;
        const float vm1 = (t >= 1) ? (xm.y - xmm.y) : 0.f;
        a0 = v0 - vm0; a1 = v1 - vm1;
      }
      float wsum = w;
#pragma unroll
      for (int m = 32; m; m >>= 1) wsum += __shfl_xor(wsum, m);
      const float wn = w * (1.f / (wsum + 1e-6f));
      lds[lane * 5 + 0] = wn * v0; lds[lane * 5 + 1] = wn * v1;
      lds[lane * 5 + 2] = wn * a0; lds[lane * 5 + 3] = wn * a1;
      lds[lane * 5 + 4] = wn;
      // wave-synchronous LDS (only this wave touches wsl[wave])
      if (lane < CROW) {
        float accv;
        if (lane == NCOEF) {
          accv = 1.0f;                      // validity flag -> H term
        } else {
          const int p = lane / 5, q = lane - p * 5;
          const int k0 = (p == 0) ? 0  : ((p == 1) ? 12 : 33);
          const int k1 = (p == 0) ? 12 : ((p == 1) ? 33 : 54);
          accv = 0.f;
          for (int k = k0; k < k1; ++k) accv += lds[k * 5 + q];
          if (q < 2) accv *= gv; else if (q < 4) accv *= ga;
        }
        coef[((size_t)b * TROWS + 1 + t) * CROW + lane] = accv;
      }
    }
    // zero pad rows: first 16 coef-blocks each write one
    if (blk < 2 * BB && tid < CROW) {
      const int b = blk >> 1, side = blk & 1;
      coef[((size_t)b * TROWS + (side ? (TT + 1) : 0)) * CROW + tid] = 0.f;
    }
  }
}

// ---------- K_B: 48-FMA (scalar-operand) matvec + LayerNorm ----------
__global__ __launch_bounds__(256) void kb_main(
    const float* __restrict__ coef, const float* __restrict__ Gt,
    const float* __restrict__ baset, const float* __restrict__ ln_w,
    const float* __restrict__ ln_b, float* __restrict__ out)
{
  const int b  = blockIdx.x >> 6;
  const int t0 = (blockIdx.x & 63) * TS;
  const int e  = threadIdx.x;
  const int wave = e >> 6, lane = e & 63;

  float Gr[48];
#pragma unroll
  for (int o = 0; o < 48; ++o) Gr[o] = Gt[o * DD + e];
  const float bs = baset[e];
  const float lw = ln_w[e], lb = ln_b[e];

  __shared__ float red[2][4][2];

  // coef row for gt = t0+tl-1+j lives at (b*TROWS + t0 + tl + j)*CROW
  const int rowbase = (b * TROWS + t0) * CROW;

#pragma unroll
  for (int tl = 0; tl < TS; ++tl) {
    float acc = bs;
#pragma unroll
    for (int j = 0; j < 3; ++j) {
      const int off = __builtin_amdgcn_readfirstlane(rowbase + (tl + j) * CROW);
      const float* cr = coef + off;       // scalar (SGPR) loads, K$-resident
#pragma unroll
      for (int i = 0; i < CROW; ++i)
        acc += cr[i] * Gr[j * CROW + i];
    }
    // LayerNorm block reduction over e
    float s = acc, ss = acc * acc;
#pragma unroll
    for (int m = 32; m; m >>= 1) { s += __shfl_xor(s, m); ss += __shfl_xor(ss, m); }
    const int par = tl & 1;
    if (lane == 0) { red[par][wave][0] = s; red[par][wave][1] = ss; }
    __syncthreads();
    const float fs  = red[par][0][0] + red[par][1][0] + red[par][2][0] + red[par][3][0];
    const float fss = red[par][0][1] + red[par][1][1] + red[par][2][1] + red[par][3][1];
    const float mu  = fs * (1.f / DD);
    const float var = fss * (1.f / DD) - mu * mu;
    const float rs  = rsqrtf(var + 1e-5f);
    out[((size_t)b * TT + t0 + tl) * DD + e] = (acc - mu) * rs * lw + lb;
  }
}

extern "C" void kernel_launch(void* const* d_in, const int* in_sizes, int n_in,
                              void* d_out, int out_size, void* d_ws, size_t ws_size,
                              hipStream_t stream) {
  const float* barX    = (const float*)d_in[0];
  const float* W       = (const float*)d_in[1];
  const float* phi_v_w = (const float*)d_in[2];
  const float* phi_v_b = (const float*)d_in[3];
  const float* phi_a_w = (const float*)d_in[4];
  const float* phi_a_b = (const float*)d_in[5];
  const float* gamma_v = (const float*)d_in[6];
  const float* gamma_a = (const float*)d_in[7];
  const float* WM_w    = (const float*)d_in[8];
  const float* WM_b    = (const float*)d_in[9];
  const float* dw_w    = (const float*)d_in[10];
  const float* dw_b    = (const float*)d_in[11];
  const float* pw_w    = (const float*)d_in[12];
  const float* pw_b    = (const float*)d_in[13];
  const float* ln_w    = (const float*)d_in[14];
  const float* ln_b    = (const float*)d_in[15];
  float* out = (float*)d_out;

  float* ws    = (float*)d_ws;
  float* Gt    = ws;            // 48*256 = 12288
  float* baset = ws + 12288;    // 256
  float* coef  = ws + 16384;    // 8*1026*16 = 131328 floats
  // total ~590KB of d_ws

  hipLaunchKernelGGL(ka_tables_coef, dim3(49 + NBT / 16), dim3(256), 0, stream,
                     barX, W, phi_v_w, phi_v_b, phi_a_w, phi_a_b,
                     gamma_v, gamma_a, WM_w, WM_b, dw_w, dw_b, pw_w, pw_b,
                     Gt, baset, coef);
  hipLaunchKernelGGL(kb_main, dim3(BB * (TT / TS)), dim3(256), 0, stream,
                     coef, Gt, baset, ln_w, ln_b, out);
}